// Round 22
// baseline (69.939 us; speedup 1.0000x reference)
//
#include <hip/hip_runtime.h>
#include <hip/hip_bf16.h>

typedef __attribute__((ext_vector_type(8))) short bf16x8;
typedef __attribute__((ext_vector_type(4))) float f32x4;
typedef __attribute__((ext_vector_type(4))) unsigned short u16x4;

#define MFMA16(a, b, c) __builtin_amdgcn_mfma_f32_16x16x32_bf16(a, b, c, 0, 0, 0)

// B=16, S=2048, EMB=512, HEAD_DIM=64
// Q pre-scaled by 0.125 * log2(e): softmax runs in exp2 domain.
#define QSCALE 0.18033688011112042f

#define GLDS16(gp, lp)                                                         \
    __builtin_amdgcn_global_load_lds(                                          \
        (const __attribute__((address_space(1))) void*)(gp),                   \
        (__attribute__((address_space(3))) void*)(lp), 16, 0, 0)

__device__ __forceinline__ short nbf(float f) {
    __hip_bfloat16 h = __float2bfloat16(f);
    return *(short*)&h;
}
__device__ __forceinline__ unsigned short nbfu(float f) {
    __hip_bfloat16 h = __float2bfloat16(f);
    return *(unsigned short*)&h;
}

// Wtf FRAGMENT-TILED: fragment (ks, n) holds W_mat[e=ks*32+g*8+j][h=(n&3)*16+c]
// for mat=n>>2, at ushort idx (ks*12+n)*512 + (g*16+c)*8 + j. qkv reads each
// fragment as one wave-contiguous 1KB burst from L2.
__global__ void wt_kernel(const float* __restrict__ Wq, const float* __restrict__ Wk,
                          const float* __restrict__ Wv, unsigned short* __restrict__ Wtf) {
    const int h = blockIdx.x;      // 0..63
    const int mat = blockIdx.y;    // 0..2
    const int e = threadIdx.x;     // 0..511
    const float* W = (mat == 0) ? Wq : ((mat == 1) ? Wk : Wv);
    const int n2 = h >> 4, c = h & 15;
    const int ks = e >> 5, g = (e >> 3) & 3, j = e & 7;
    Wtf[(size_t)(ks * 12 + mat * 4 + n2) * 512 + (g * 16 + c) * 8 + j] = nbfu(W[e * 64 + h]);
}

// Fused QKV projection v7: A (x1, HBM) staged via GLDS double-buffer as before;
// B read DIRECTLY from fragment-tiled Wtf (L2-resident, wave-contiguous 1KB
// bursts) — no B staging, no blds, per-step drain covers only 2 A-chunks.
__global__ __launch_bounds__(512, 1) void qkv_proj(
    const float* __restrict__ x1, const unsigned short* __restrict__ Wtf,
    unsigned short* __restrict__ Q, unsigned short* __restrict__ Kf,
    unsigned short* __restrict__ Vf)
{
    __shared__ char alds[2][16384];   // A: [128 tok][8 slots]x16B, slot qp holds q=qp^(tok&7)

    const int tid = threadIdx.x;
    const int W = tid >> 6, lane = tid & 63;
    const int c = lane & 15, g = lane >> 4;
    const int tokB = blockIdx.x * 128;

    const char* x1b = (const char*)x1;
    const char* Wtfb = (const char*)Wtf;

    const int tA0 = tid >> 3,           qA0 = (tid & 7) ^ (tA0 & 7);
    const int tA1 = (tid + 512) >> 3,   qA1 = (tid & 7) ^ (tA1 & 7);
    const size_t aoff0 = (size_t)(tokB + tA0) * 2048 + qA0 * 16;
    const size_t aoff1 = (size_t)(tokB + tA1) * 2048 + qA1 * 16;

    f32x4 acc[12];
#pragma unroll
    for (int n = 0; n < 12; ++n) acc[n] = (f32x4)0.f;

    GLDS16(x1b + aoff0, &alds[0][tid * 16]);
    GLDS16(x1b + aoff1, &alds[0][8192 + tid * 16]);

    const int arow = (W * 16 + c) * 128;
    const int aq0 = (((2 * g) ^ (c & 7)) * 16);
    const int aq1 = (((2 * g + 1) ^ (c & 7)) * 16);

    int buf = 0;
    for (int ks = 0; ks < 16; ++ks) {
        asm volatile("s_waitcnt vmcnt(0)\n\ts_barrier" ::: "memory");

        if (ks < 15) {
            const size_t ka = (size_t)(ks + 1) * 128;
            char* ab = &alds[buf ^ 1][0];
            GLDS16(x1b + aoff0 + ka, ab + tid * 16);
            GLDS16(x1b + aoff1 + ka, ab + 8192 + tid * 16);
        }

        const char* ab = &alds[buf][0];
        const char* bb = Wtfb + ((size_t)ks * 12 << 10) + lane * 16;
        f32x4 a0 = *(const f32x4*)(ab + arow + aq0);
        f32x4 a1 = *(const f32x4*)(ab + arow + aq1);
        bf16x8 af;
        af[0] = nbf(a0[0]); af[1] = nbf(a0[1]); af[2] = nbf(a0[2]); af[3] = nbf(a0[3]);
        af[4] = nbf(a1[0]); af[5] = nbf(a1[1]); af[6] = nbf(a1[2]); af[7] = nbf(a1[3]);
#pragma unroll
        for (int n = 0; n < 12; ++n) {
            bf16x8 bf = *(const bf16x8*)(bb + (n << 10));
            acc[n] = MFMA16(af, bf, acc[n]);
        }
        buf ^= 1;
    }

    const int tok0 = tokB + W * 16;
    const int bb2 = tokB >> 11;
    const int ht = ((tokB & 2047) >> 6) + (W >> 2);

#pragma unroll
    for (int n = 0; n < 4; ++n)
#pragma unroll
        for (int r = 0; r < 4; ++r)
            Q[(size_t)(tok0 + g * 4 + r) * 64 + n * 16 + c] = nbfu(acc[n][r] * QSCALE);

    {
        unsigned short* kf = Kf + (size_t)bb2 * 131072 + (size_t)ht * 4096;
#pragma unroll
        for (int n = 0; n < 4; ++n) {
            const int gf = (n & 1) * 2 + (c >> 3);
            const size_t base = (size_t)(n >> 1) * 2048 + (W & 3) * 512 + (c & 7);
#pragma unroll
            for (int r = 0; r < 4; ++r)
                kf[base + (size_t)(gf * 16 + g * 4 + r) * 8] = nbfu(acc[4 + n][r]);
        }
    }

    {
        unsigned short* vf = Vf + (size_t)bb2 * 131072 + (size_t)ht * 4096;
        const int sub = (W & 3) >> 1;
        const int gf = (W & 1) * 2 + (g >> 1);
        const int jb = (g & 1) * 4;
#pragma unroll
        for (int n = 0; n < 4; ++n) {
            u16x4 pv;
#pragma unroll
            for (int r = 0; r < 4; ++r) pv[r] = nbfu(acc[8 + n][r]);
            *(u16x4*)(vf + (size_t)sub * 2048 + n * 512 + (gf * 16 + c) * 8 + jb) = pv;
        }
    }
}

// Causal flash attention v13b (R20 verbatim — best known: 54.1us total).
__global__ __launch_bounds__(512, 4) void flash_attn(
    const unsigned short* __restrict__ Q, const unsigned short* __restrict__ Kf,
    const unsigned short* __restrict__ Vf, float* __restrict__ out)
{
    __shared__ char p_lds[32768];   // [wave 0..7][ps=4][lane=64]x16B; reused for merge
    __shared__ float mb[4][16], lb[4][16];

    const int tid = threadIdx.x;
    const int W = tid >> 6;
    const int st = W >> 2;
    const int w = W & 3;
    const int lane = tid & 63;
    const int c = lane & 15, g = lane >> 4;

    const int id = blockIdx.x;
    const int b = 2 * (id & 7) + ((id >> 3) & 1);
    const int k = id >> 4;                         // 0..31
    const int qt = (k < 16) ? (31 - k) : (k - 16); // pair (k,k+16): qt sum = 31
    const int n2 = (qt >> 1) + 1;                  // # 128-key tiles
    const int qr0c = qt * 64 + w * 16 + c;
    const size_t qrow_g = ((size_t)b << 11) + qt * 64 + w * 16;

    bf16x8 qf0 = *(const bf16x8*)(Q + (qrow_g + c) * 64 + g * 8);
    bf16x8 qf1 = *(const bf16x8*)(Q + (qrow_g + c) * 64 + 32 + g * 8);

    const char* Kfb = (const char*)(Kf + (size_t)b * 131072);
    const char* Vfb = (const char*)(Vf + (size_t)b * 131072);

    float m = -1e30f, l = 0.f;
    f32x4 acc[4];
#pragma unroll
    for (int n = 0; n < 4; ++n) acc[n] = (f32x4)0.f;

    for (int t = st; t < n2; t += 2) {
        const char* kt = Kfb + (size_t)t * 16384;
        const char* vt = Vfb + (size_t)t * 16384;

        f32x4 s[8];
#pragma unroll
        for (int i = 0; i < 8; ++i) s[i] = (f32x4)0.f;
#pragma unroll
        for (int h = 0; h < 2; ++h) {
            bf16x8 ka[4], kb2[4];
#pragma unroll
            for (int n = 0; n < 4; ++n) {
                ka[n]  = *(const bf16x8*)(kt + h * 8192 + n * 1024 + lane * 16);
                kb2[n] = *(const bf16x8*)(kt + h * 8192 + 4096 + n * 1024 + lane * 16);
            }
            __builtin_amdgcn_s_setprio(1);
#pragma unroll
            for (int n = 0; n < 4; ++n) {
                s[h * 4 + n] = MFMA16(ka[n], qf0, s[h * 4 + n]);
                s[h * 4 + n] = MFMA16(kb2[n], qf1, s[h * 4 + n]);
            }
            __builtin_amdgcn_s_setprio(0);
        }

        // ---- hoisted V loads (ps = 0,1): latency hides under softmax ----
        bf16x8 vf01[8];
#pragma unroll
        for (int ps = 0; ps < 2; ++ps)
#pragma unroll
            for (int n = 0; n < 4; ++n)
                vf01[ps * 4 + n] = *(const bf16x8*)(vt + (ps & 1) * 4096 + n * 1024 + lane * 16);

        if (t == n2 - 1) {
#pragma unroll
            for (int h = 0; h < 2; ++h)
#pragma unroll
                for (int n = 0; n < 4; ++n) {
                    const int key0 = t * 128 + h * 64 + n * 16 + g * 4;
#pragma unroll
                    for (int r = 0; r < 4; ++r)
                        if (key0 + r > qr0c) s[h * 4 + n][r] = -1e30f;
                }
        }

        float tm = -1e30f;
#pragma unroll
        for (int i = 0; i < 8; ++i)
            tm = fmaxf(tm, fmaxf(fmaxf(s[i][0], s[i][1]), fmaxf(s[i][2], s[i][3])));

        if (__any(tm > m + 8.f)) {
            float gm = tm;
            gm = fmaxf(gm, __shfl_xor(gm, 16, 64));
            gm = fmaxf(gm, __shfl_xor(gm, 32, 64));
            const float mn = fmaxf(m, gm);
            const float alpha = exp2f(m - mn);
            m = mn;
            l *= alpha;
            float al[4];
#pragma unroll
            for (int r = 0; r < 4; ++r) al[r] = __shfl(alpha, g * 4 + r, 16);
#pragma unroll
            for (int n = 0; n < 4; ++n)
#pragma unroll
                for (int r = 0; r < 4; ++r) acc[n][r] *= al[r];
        }

        char* pw = &p_lds[W * 4096 + ((g >> 1) * 16 + c) * 16 + (g & 1) * 8];
#pragma unroll
        for (int h = 0; h < 2; ++h)
#pragma unroll
            for (int n = 0; n < 4; ++n) {
                const int i = h * 4 + n;
                float p0 = exp2f(s[i][0] - m);
                float p1 = exp2f(s[i][1] - m);
                float p2 = exp2f(s[i][2] - m);
                float p3 = exp2f(s[i][3] - m);
                l += (p0 + p1) + (p2 + p3);
                u16x4 pk;
                pk[0] = nbfu(p0); pk[1] = nbfu(p1); pk[2] = nbfu(p2); pk[3] = nbfu(p3);
                *(u16x4*)(pw + (h * 2 + (n >> 1)) * 1024 + (n & 1) * 512) = pk;
            }

        const char* pr = &p_lds[W * 4096 + lane * 16];
        // ps = 0,1 : V already in registers
#pragma unroll
        for (int ps = 0; ps < 2; ++ps) {
            bf16x8 pf = *(const bf16x8*)(pr + ps * 1024);
            __builtin_amdgcn_s_setprio(1);
#pragma unroll
            for (int n = 0; n < 4; ++n)
                acc[n] = MFMA16(pf, vf01[ps * 4 + n], acc[n]);
            __builtin_amdgcn_s_setprio(0);
        }
        // ps = 2,3 : load in place (latency covered by ps 0,1 MFMAs)
#pragma unroll
        for (int ps = 2; ps < 4; ++ps) {
            bf16x8 pf = *(const bf16x8*)(pr + ps * 1024);
            bf16x8 vf[4];
#pragma unroll
            for (int n = 0; n < 4; ++n)
                vf[n] = *(const bf16x8*)(vt + 8192 + (ps & 1) * 4096 + n * 1024 + lane * 16);
            __builtin_amdgcn_s_setprio(1);
#pragma unroll
            for (int n = 0; n < 4; ++n)
                acc[n] = MFMA16(pf, vf[n], acc[n]);
            __builtin_amdgcn_s_setprio(0);
        }
    }

    __syncthreads();
    float* accb = (float*)&p_lds[0];   // [w=4][row=16][col=64] f32 = 16KB

    if (st == 1) {
        l += __shfl_xor(l, 16, 64);
        l += __shfl_xor(l, 32, 64);
        if (g == 0) { mb[w][c] = m; lb[w][c] = l; }
#pragma unroll
        for (int n = 0; n < 4; ++n)
#pragma unroll
            for (int r = 0; r < 4; ++r)
                accb[w * 1024 + (g * 4 + r) * 64 + n * 16 + c] = acc[n][r];
    }
    __syncthreads();

    if (st == 0) {
        l += __shfl_xor(l, 16, 64);
        l += __shfl_xor(l, 32, 64);
        const float m1c = mb[w][c];
        const float l1c = lb[w][c];
        const float mF = fmaxf(m, m1c);
        const float a0 = exp2f(m - mF);                        // set 0 always non-empty
        const float a1 = (m1c > -1e29f) ? exp2f(m1c - mF) : 0.f;
        const float inv = 1.f / (l * a0 + l1c * a1);
        const float s0 = a0 * inv, s1 = a1 * inv;
        float s0r[4], s1r[4];
#pragma unroll
        for (int r = 0; r < 4; ++r) {
            s0r[r] = __shfl(s0, g * 4 + r, 16);
            s1r[r] = __shfl(s1, g * 4 + r, 16);
        }
#pragma unroll
        for (int n = 0; n < 4; ++n)
#pragma unroll
            for (int r = 0; r < 4; ++r) {
                const float a1v = accb[w * 1024 + (g * 4 + r) * 64 + n * 16 + c];
                out[(qrow_g + g * 4 + r) * 64 + n * 16 + c] = acc[n][r] * s0r[r] + a1v * s1r[r];
            }
    }
}

extern "C" void kernel_launch(void* const* d_in, const int* in_sizes, int n_in,
                              void* d_out, int out_size, void* d_ws, size_t ws_size,
                              hipStream_t stream) {
    const float* x1 = (const float*)d_in[0];
    const float* Wq = (const float*)d_in[2];
    const float* Wk = (const float*)d_in[3];
    const float* Wv = (const float*)d_in[4];
    float* out = (float*)d_out;

    unsigned short* Wtf = (unsigned short*)d_ws;
    unsigned short* Qw  = (unsigned short*)((char*)d_ws + 196608);
    unsigned short* Kfw = (unsigned short*)((char*)d_ws + 196608 + 4194304);
    unsigned short* Vfw = (unsigned short*)((char*)d_ws + 196608 + 2 * 4194304);

    wt_kernel<<<dim3(64, 3), 512, 0, stream>>>(Wq, Wk, Wv, Wtf);
    qkv_proj<<<256, 512, 0, stream>>>(x1, Wtf, Qw, Kfw, Vfw);
    flash_attn<<<512, 512, 0, stream>>>(Qw, Kfw, Vfw, out);
}

// Round 23
// 54.433 us; speedup vs baseline: 1.2849x; 1.2849x over previous
//
#include <hip/hip_runtime.h>
#include <hip/hip_bf16.h>

typedef __attribute__((ext_vector_type(8))) short bf16x8;
typedef __attribute__((ext_vector_type(4))) float f32x4;
typedef __attribute__((ext_vector_type(4))) unsigned short u16x4;

#define MFMA16(a, b, c) __builtin_amdgcn_mfma_f32_16x16x32_bf16(a, b, c, 0, 0, 0)

// B=16, S=2048, EMB=512, HEAD_DIM=64
// Q pre-scaled by 0.125 * log2(e): softmax runs in exp2 domain.
#define QSCALE 0.18033688011112042f

#define GLDS16(gp, lp)                                                         \
    __builtin_amdgcn_global_load_lds(                                          \
        (const __attribute__((address_space(1))) void*)(gp),                   \
        (__attribute__((address_space(3))) void*)(lp), 16, 0, 0)

__device__ __forceinline__ short nbf(float f) {
    __hip_bfloat16 h = __float2bfloat16(f);
    return *(short*)&h;
}
__device__ __forceinline__ unsigned short nbfu(float f) {
    __hip_bfloat16 h = __float2bfloat16(f);
    return *(unsigned short*)&h;
}

__global__ void wt_kernel(const float* __restrict__ Wq, const float* __restrict__ Wk,
                          const float* __restrict__ Wv, unsigned short* __restrict__ Wt) {
    const int h = blockIdx.x;
    const int mat = blockIdx.y;
    const int e = threadIdx.x;
    const float* W = (mat == 0) ? Wq : ((mat == 1) ? Wk : Wv);
    Wt[(mat * 64 + h) * 512 + e] = nbfu(W[e * 64 + h]);
}

// Fused QKV projection v5 (R20 verbatim): A (x1, HBM) + B (Wt, L2) both staged
// via GLDS double-buffer; single barrier per k-step; writes fragment-tiled
// Kf/Vf so flash staging/loads are wave-contiguous.
// NOTE (R22 lesson): direct-global B reads regress here — at 1 block/CU there
// is no co-resident work to cover L2 latency, and plain loads get sunk to use
// sites (VGPR=44). GLDS staging is un-sinkable; keep it.
__global__ __launch_bounds__(512, 1) void qkv_proj(
    const float* __restrict__ x1, const unsigned short* __restrict__ Wt,
    unsigned short* __restrict__ Q, unsigned short* __restrict__ Kf,
    unsigned short* __restrict__ Vf)
{
    __shared__ char alds[2][16384];
    __shared__ char blds[2][12288];

    const int tid = threadIdx.x;
    const int W = tid >> 6, lane = tid & 63;
    const int c = lane & 15, g = lane >> 4;
    const int tokB = blockIdx.x * 128;

    const char* x1b = (const char*)x1;
    const char* Wtb = (const char*)Wt;

    const int tA0 = tid >> 3,           qA0 = (tid & 7) ^ (tA0 & 7);
    const int tA1 = (tid + 512) >> 3,   qA1 = (tid & 7) ^ (tA1 & 7);
    const size_t aoff0 = (size_t)(tokB + tA0) * 2048 + qA0 * 16;
    const size_t aoff1 = (size_t)(tokB + tA1) * 2048 + qA1 * 16;

    auto bsrc = [&](int j) -> size_t {
        const int n = j >> 6, c2 = (j >> 2) & 15, g2 = j & 3;
        return (size_t)((n >> 2) * 64 + (n & 3) * 16 + c2) * 1024 + g2 * 16;
    };
    const size_t boff0 = bsrc(tid), boff1 = bsrc(tid + 512);

    f32x4 acc[12];
#pragma unroll
    for (int n = 0; n < 12; ++n) acc[n] = (f32x4)0.f;

    GLDS16(x1b + aoff0, &alds[0][tid * 16]);
    GLDS16(x1b + aoff1, &alds[0][8192 + tid * 16]);
    GLDS16(Wtb + boff0, &blds[0][tid * 16]);
    if (tid < 256) GLDS16(Wtb + boff1, &blds[0][8192 + tid * 16]);

    const int arow = (W * 16 + c) * 128;
    const int aq0 = (((2 * g) ^ (c & 7)) * 16);
    const int aq1 = (((2 * g + 1) ^ (c & 7)) * 16);
    const int brd = (c * 4 + g) * 16;

    int buf = 0;
    for (int ks = 0; ks < 16; ++ks) {
        asm volatile("s_waitcnt vmcnt(0)\n\ts_barrier" ::: "memory");

        if (ks < 15) {
            const size_t ka = (size_t)(ks + 1) * 128;
            const size_t kb = (size_t)(ks + 1) * 64;
            char* ab = &alds[buf ^ 1][0];
            char* bb = &blds[buf ^ 1][0];
            GLDS16(x1b + aoff0 + ka, ab + tid * 16);
            GLDS16(x1b + aoff1 + ka, ab + 8192 + tid * 16);
            GLDS16(Wtb + boff0 + kb, bb + tid * 16);
            if (tid < 256) GLDS16(Wtb + boff1 + kb, bb + 8192 + tid * 16);
        }

        const char* ab = &alds[buf][0];
        const char* bb = &blds[buf][0];
        f32x4 a0 = *(const f32x4*)(ab + arow + aq0);
        f32x4 a1 = *(const f32x4*)(ab + arow + aq1);
        bf16x8 af;
        af[0] = nbf(a0[0]); af[1] = nbf(a0[1]); af[2] = nbf(a0[2]); af[3] = nbf(a0[3]);
        af[4] = nbf(a1[0]); af[5] = nbf(a1[1]); af[6] = nbf(a1[2]); af[7] = nbf(a1[3]);
#pragma unroll
        for (int n = 0; n < 12; ++n) {
            bf16x8 bf = *(const bf16x8*)(bb + n * 1024 + brd);
            acc[n] = MFMA16(af, bf, acc[n]);
        }
        buf ^= 1;
    }

    const int tok0 = tokB + W * 16;
    const int bb2 = tokB >> 11;
    const int ht = ((tokB & 2047) >> 6) + (W >> 2);

#pragma unroll
    for (int n = 0; n < 4; ++n)
#pragma unroll
        for (int r = 0; r < 4; ++r)
            Q[(size_t)(tok0 + g * 4 + r) * 64 + n * 16 + c] = nbfu(acc[n][r] * QSCALE);

    {
        unsigned short* kf = Kf + (size_t)bb2 * 131072 + (size_t)ht * 4096;
#pragma unroll
        for (int n = 0; n < 4; ++n) {
            const int gf = (n & 1) * 2 + (c >> 3);
            const size_t base = (size_t)(n >> 1) * 2048 + (W & 3) * 512 + (c & 7);
#pragma unroll
            for (int r = 0; r < 4; ++r)
                kf[base + (size_t)(gf * 16 + g * 4 + r) * 8] = nbfu(acc[4 + n][r]);
        }
    }

    {
        unsigned short* vf = Vf + (size_t)bb2 * 131072 + (size_t)ht * 4096;
        const int sub = (W & 3) >> 1;
        const int gf = (W & 1) * 2 + (g >> 1);
        const int jb = (g & 1) * 4;
#pragma unroll
        for (int n = 0; n < 4; ++n) {
            u16x4 pv;
#pragma unroll
            for (int r = 0; r < 4; ++r) pv[r] = nbfu(acc[8 + n][r]);
            *(u16x4*)(vf + (size_t)sub * 2048 + n * 512 + (gf * 16 + c) * 8 + jb) = pv;
        }
    }
}

// Causal flash attention v13b (R20 verbatim — best known: 54.06us total).
__global__ __launch_bounds__(512, 4) void flash_attn(
    const unsigned short* __restrict__ Q, const unsigned short* __restrict__ Kf,
    const unsigned short* __restrict__ Vf, float* __restrict__ out)
{
    __shared__ char p_lds[32768];   // [wave 0..7][ps=4][lane=64]x16B; reused for merge
    __shared__ float mb[4][16], lb[4][16];

    const int tid = threadIdx.x;
    const int W = tid >> 6;
    const int st = W >> 2;
    const int w = W & 3;
    const int lane = tid & 63;
    const int c = lane & 15, g = lane >> 4;

    const int id = blockIdx.x;
    const int b = 2 * (id & 7) + ((id >> 3) & 1);
    const int k = id >> 4;                         // 0..31
    const int qt = (k < 16) ? (31 - k) : (k - 16); // pair (k,k+16): qt sum = 31
    const int n2 = (qt >> 1) + 1;                  // # 128-key tiles
    const int qr0c = qt * 64 + w * 16 + c;
    const size_t qrow_g = ((size_t)b << 11) + qt * 64 + w * 16;

    bf16x8 qf0 = *(const bf16x8*)(Q + (qrow_g + c) * 64 + g * 8);
    bf16x8 qf1 = *(const bf16x8*)(Q + (qrow_g + c) * 64 + 32 + g * 8);

    const char* Kfb = (const char*)(Kf + (size_t)b * 131072);
    const char* Vfb = (const char*)(Vf + (size_t)b * 131072);

    float m = -1e30f, l = 0.f;
    f32x4 acc[4];
#pragma unroll
    for (int n = 0; n < 4; ++n) acc[n] = (f32x4)0.f;

    for (int t = st; t < n2; t += 2) {
        const char* kt = Kfb + (size_t)t * 16384;
        const char* vt = Vfb + (size_t)t * 16384;

        f32x4 s[8];
#pragma unroll
        for (int i = 0; i < 8; ++i) s[i] = (f32x4)0.f;
#pragma unroll
        for (int h = 0; h < 2; ++h) {
            bf16x8 ka[4], kb2[4];
#pragma unroll
            for (int n = 0; n < 4; ++n) {
                ka[n]  = *(const bf16x8*)(kt + h * 8192 + n * 1024 + lane * 16);
                kb2[n] = *(const bf16x8*)(kt + h * 8192 + 4096 + n * 1024 + lane * 16);
            }
            __builtin_amdgcn_s_setprio(1);
#pragma unroll
            for (int n = 0; n < 4; ++n) {
                s[h * 4 + n] = MFMA16(ka[n], qf0, s[h * 4 + n]);
                s[h * 4 + n] = MFMA16(kb2[n], qf1, s[h * 4 + n]);
            }
            __builtin_amdgcn_s_setprio(0);
        }

        // ---- hoisted V loads (ps = 0,1): latency hides under softmax ----
        bf16x8 vf01[8];
#pragma unroll
        for (int ps = 0; ps < 2; ++ps)
#pragma unroll
            for (int n = 0; n < 4; ++n)
                vf01[ps * 4 + n] = *(const bf16x8*)(vt + (ps & 1) * 4096 + n * 1024 + lane * 16);

        if (t == n2 - 1) {
#pragma unroll
            for (int h = 0; h < 2; ++h)
#pragma unroll
                for (int n = 0; n < 4; ++n) {
                    const int key0 = t * 128 + h * 64 + n * 16 + g * 4;
#pragma unroll
                    for (int r = 0; r < 4; ++r)
                        if (key0 + r > qr0c) s[h * 4 + n][r] = -1e30f;
                }
        }

        float tm = -1e30f;
#pragma unroll
        for (int i = 0; i < 8; ++i)
            tm = fmaxf(tm, fmaxf(fmaxf(s[i][0], s[i][1]), fmaxf(s[i][2], s[i][3])));

        if (__any(tm > m + 8.f)) {
            float gm = tm;
            gm = fmaxf(gm, __shfl_xor(gm, 16, 64));
            gm = fmaxf(gm, __shfl_xor(gm, 32, 64));
            const float mn = fmaxf(m, gm);
            const float alpha = exp2f(m - mn);
            m = mn;
            l *= alpha;
            float al[4];
#pragma unroll
            for (int r = 0; r < 4; ++r) al[r] = __shfl(alpha, g * 4 + r, 16);
#pragma unroll
            for (int n = 0; n < 4; ++n)
#pragma unroll
                for (int r = 0; r < 4; ++r) acc[n][r] *= al[r];
        }

        char* pw = &p_lds[W * 4096 + ((g >> 1) * 16 + c) * 16 + (g & 1) * 8];
#pragma unroll
        for (int h = 0; h < 2; ++h)
#pragma unroll
            for (int n = 0; n < 4; ++n) {
                const int i = h * 4 + n;
                float p0 = exp2f(s[i][0] - m);
                float p1 = exp2f(s[i][1] - m);
                float p2 = exp2f(s[i][2] - m);
                float p3 = exp2f(s[i][3] - m);
                l += (p0 + p1) + (p2 + p3);
                u16x4 pk;
                pk[0] = nbfu(p0); pk[1] = nbfu(p1); pk[2] = nbfu(p2); pk[3] = nbfu(p3);
                *(u16x4*)(pw + (h * 2 + (n >> 1)) * 1024 + (n & 1) * 512) = pk;
            }

        const char* pr = &p_lds[W * 4096 + lane * 16];
        // ps = 0,1 : V already in registers
#pragma unroll
        for (int ps = 0; ps < 2; ++ps) {
            bf16x8 pf = *(const bf16x8*)(pr + ps * 1024);
            __builtin_amdgcn_s_setprio(1);
#pragma unroll
            for (int n = 0; n < 4; ++n)
                acc[n] = MFMA16(pf, vf01[ps * 4 + n], acc[n]);
            __builtin_amdgcn_s_setprio(0);
        }
        // ps = 2,3 : load in place (latency covered by ps 0,1 MFMAs)
#pragma unroll
        for (int ps = 2; ps < 4; ++ps) {
            bf16x8 pf = *(const bf16x8*)(pr + ps * 1024);
            bf16x8 vf[4];
#pragma unroll
            for (int n = 0; n < 4; ++n)
                vf[n] = *(const bf16x8*)(vt + 8192 + (ps & 1) * 4096 + n * 1024 + lane * 16);
            __builtin_amdgcn_s_setprio(1);
#pragma unroll
            for (int n = 0; n < 4; ++n)
                acc[n] = MFMA16(pf, vf[n], acc[n]);
            __builtin_amdgcn_s_setprio(0);
        }
    }

    __syncthreads();
    float* accb = (float*)&p_lds[0];   // [w=4][row=16][col=64] f32 = 16KB

    if (st == 1) {
        l += __shfl_xor(l, 16, 64);
        l += __shfl_xor(l, 32, 64);
        if (g == 0) { mb[w][c] = m; lb[w][c] = l; }
#pragma unroll
        for (int n = 0; n < 4; ++n)
#pragma unroll
            for (int r = 0; r < 4; ++r)
                accb[w * 1024 + (g * 4 + r) * 64 + n * 16 + c] = acc[n][r];
    }
    __syncthreads();

    if (st == 0) {
        l += __shfl_xor(l, 16, 64);
        l += __shfl_xor(l, 32, 64);
        const float m1c = mb[w][c];
        const float l1c = lb[w][c];
        const float mF = fmaxf(m, m1c);
        const float a0 = exp2f(m - mF);                        // set 0 always non-empty
        const float a1 = (m1c > -1e29f) ? exp2f(m1c - mF) : 0.f;
        const float inv = 1.f / (l * a0 + l1c * a1);
        const float s0 = a0 * inv, s1 = a1 * inv;
        float s0r[4], s1r[4];
#pragma unroll
        for (int r = 0; r < 4; ++r) {
            s0r[r] = __shfl(s0, g * 4 + r, 16);
            s1r[r] = __shfl(s1, g * 4 + r, 16);
        }
#pragma unroll
        for (int n = 0; n < 4; ++n)
#pragma unroll
            for (int r = 0; r < 4; ++r) {
                const float a1v = accb[w * 1024 + (g * 4 + r) * 64 + n * 16 + c];
                out[(qrow_g + g * 4 + r) * 64 + n * 16 + c] = acc[n][r] * s0r[r] + a1v * s1r[r];
            }
    }
}

extern "C" void kernel_launch(void* const* d_in, const int* in_sizes, int n_in,
                              void* d_out, int out_size, void* d_ws, size_t ws_size,
                              hipStream_t stream) {
    const float* x1 = (const float*)d_in[0];
    const float* Wq = (const float*)d_in[2];
    const float* Wk = (const float*)d_in[3];
    const float* Wv = (const float*)d_in[4];
    float* out = (float*)d_out;

    unsigned short* Wt  = (unsigned short*)d_ws;
    unsigned short* Qw  = (unsigned short*)((char*)d_ws + 196608);
    unsigned short* Kfw = (unsigned short*)((char*)d_ws + 196608 + 4194304);
    unsigned short* Vfw = (unsigned short*)((char*)d_ws + 196608 + 2 * 4194304);

    wt_kernel<<<dim3(64, 3), 512, 0, stream>>>(Wq, Wk, Wv, Wt);
    qkv_proj<<<256, 512, 0, stream>>>(x1, Wt, Qw, Kfw, Vfw);
    flash_attn<<<512, 512, 0, stream>>>(Qw, Kfw, Vfw, out);
}